// Round 1
// baseline (15543.942 us; speedup 1.0000x reference)
//
#include <hip/hip_runtime.h>

#define Bb 256
#define Tt 512
#define Dd 512
#define Hh 512
#define KTOT 1024
#define FOURH 2048

#define BM 32
#define BN 32
#define KC 128
#define APAD 8

typedef __attribute__((ext_vector_type(8))) short bf16x8;
typedef __attribute__((ext_vector_type(4))) float f32x4;

__device__ __forceinline__ unsigned short f2bf(float f) {
    union { float f; unsigned u; } x; x.f = f;
    unsigned u = x.u;
    unsigned r = u + 0x7FFFu + ((u >> 16) & 1u);
    return (unsigned short)(r >> 16);
}
__device__ __forceinline__ float bf2f(unsigned short s) {
    union { unsigned u; float f; } x; x.u = ((unsigned)s) << 16;
    return x.f;
}

// Transpose + split W = [Wx; Wh] (K=1024 rows, N=2048 cols) into
// WT_hi/WT_lo layout [N=2048][K=1024] bf16 (k-contiguous per output column).
__global__ void prep_w(const float* __restrict__ Wx, const float* __restrict__ Wh,
                       unsigned short* __restrict__ WT_hi, unsigned short* __restrict__ WT_lo) {
    __shared__ float tile[32][33];
    int n0 = (blockIdx.x & 63) * 32;   // 2048/32 = 64
    int k0 = (blockIdx.x >> 6) * 32;   // 1024/32 = 32
    int tx = threadIdx.x & 31;
    int ty = threadIdx.x >> 5;         // 0..7
    for (int q = 0; q < 4; ++q) {
        int k = k0 + ty + q * 8;
        int n = n0 + tx;
        float v = (k < Dd) ? Wx[(size_t)k * FOURH + n] : Wh[(size_t)(k - Dd) * FOURH + n];
        tile[ty + q * 8][tx] = v;
    }
    __syncthreads();
    for (int q = 0; q < 4; ++q) {
        int nl = ty + q * 8;
        int kl = tx;
        float v = tile[kl][nl];
        unsigned short hi = f2bf(v);
        unsigned short lo = f2bf(v - bf2f(hi));
        size_t o = (size_t)(n0 + nl) * KTOT + (size_t)(k0 + kl);
        WT_hi[o] = hi;
        WT_lo[o] = lo;
    }
}

__global__ void init_state(float* __restrict__ c_st,
                           unsigned short* __restrict__ h_hi,
                           unsigned short* __restrict__ h_lo) {
    int i = blockIdx.x * blockDim.x + threadIdx.x;
    if (i < Bb * Hh) { c_st[i] = 0.f; h_hi[i] = 0; h_lo[i] = 0; }
}

// One timestep: z = [x_t ; h] @ [Wx; Wh] (bf16x3 MFMA, fp32 accum) + b,
// gates, c/h update, conditional output write. Fused in one kernel.
// Grid: 128 WGs of 256 threads. WG tile: 32 rows x 32 h-cols.
// Wave w (0..3) computes gate w's 32x32 z-tile.
__global__ __launch_bounds__(256, 1) void lstm_step(
    const float* __restrict__ X, const int* __restrict__ lengths,
    const unsigned short* __restrict__ WT_hi, const unsigned short* __restrict__ WT_lo,
    const float* __restrict__ bias,
    float* __restrict__ c_st, unsigned short* __restrict__ h_hi, unsigned short* __restrict__ h_lo,
    float* __restrict__ out, int t)
{
    __shared__ __align__(16) unsigned short Ahi[BM][KC + APAD];
    __shared__ __align__(16) unsigned short Alo[BM][KC + APAD];
    __shared__ float zbuf[4][BM][BN + 1];

    int bx = blockIdx.x;
    int m0 = (bx & 7) * BM;     // 8 row-tiles
    int c0 = (bx >> 3) * BN;    // 16 col-tiles
    int tid = threadIdx.x;
    int w = tid >> 6;           // wave id == gate id
    int lane = tid & 63;

    f32x4 acc[2][2];
#pragma unroll
    for (int mi = 0; mi < 2; ++mi)
#pragma unroll
        for (int ni = 0; ni < 2; ++ni)
            acc[mi][ni] = (f32x4){0.f, 0.f, 0.f, 0.f};

    for (int kc = 0; kc < KTOT; kc += KC) {
        // ---- stage A chunk (32 rows x 128 k) into LDS as bf16 hi/lo ----
        if (kc < Dd) {
            // x part: convert fp32 -> hi/lo
#pragma unroll
            for (int q = 0; q < 4; ++q) {
                int li = tid + q * 256;          // 0..1023 float4 slots
                int r = li >> 5;                 // 32 float4 per row
                int f4 = li & 31;
                const float4 v = *(const float4*)&X[((size_t)(m0 + r) * Tt + t) * Dd + kc + f4 * 4];
                float vv[4] = {v.x, v.y, v.z, v.w};
#pragma unroll
                for (int e = 0; e < 4; ++e) {
                    unsigned short hi = f2bf(vv[e]);
                    Ahi[r][f4 * 4 + e] = hi;
                    Alo[r][f4 * 4 + e] = f2bf(vv[e] - bf2f(hi));
                }
            }
        } else {
            int kh = kc - Dd;
#pragma unroll
            for (int q = 0; q < 4; ++q) {
                int li = tid + q * 256;          // 0..1023 16B slots
                int arr = li >> 9;               // 0: hi, 1: lo
                int li2 = li & 511;
                int r = li2 >> 4;                // 16 x 16B per row
                int s8 = li2 & 15;
                const unsigned short* srcbase = arr ? h_lo : h_hi;
                unsigned short* dstbase = arr ? &Alo[0][0] : &Ahi[0][0];
                uint4 v = *(const uint4*)(srcbase + (size_t)(m0 + r) * Hh + kh + s8 * 8);
                *(uint4*)(dstbase + r * (KC + APAD) + s8 * 8) = v;
            }
        }
        __syncthreads();

        // ---- MFMA over this K chunk ----
#pragma unroll
        for (int ks = 0; ks < KC / 32; ++ks) {
            bf16x8 ah[2], al[2];
#pragma unroll
            for (int mi = 0; mi < 2; ++mi) {
                int row = mi * 16 + (lane & 15);
                int koff = ks * 32 + (lane >> 4) * 8;
                ah[mi] = *(const bf16x8*)&Ahi[row][koff];
                al[mi] = *(const bf16x8*)&Alo[row][koff];
            }
#pragma unroll
            for (int ni = 0; ni < 2; ++ni) {
                int col_g = w * 512 + c0 + ni * 16 + (lane & 15);
                size_t bo = (size_t)col_g * KTOT + kc + ks * 32 + (lane >> 4) * 8;
                bf16x8 bh = *(const bf16x8*)&WT_hi[bo];
                bf16x8 bl = *(const bf16x8*)&WT_lo[bo];
#pragma unroll
                for (int mi = 0; mi < 2; ++mi) {
                    acc[mi][ni] = __builtin_amdgcn_mfma_f32_16x16x32_bf16(ah[mi], bh, acc[mi][ni], 0, 0, 0);
                    acc[mi][ni] = __builtin_amdgcn_mfma_f32_16x16x32_bf16(ah[mi], bl, acc[mi][ni], 0, 0, 0);
                    acc[mi][ni] = __builtin_amdgcn_mfma_f32_16x16x32_bf16(al[mi], bh, acc[mi][ni], 0, 0, 0);
                }
            }
        }
        __syncthreads();
    }

    // ---- write z tiles to LDS (C/D layout: col=lane&15, row=(lane>>4)*4+reg) ----
#pragma unroll
    for (int mi = 0; mi < 2; ++mi)
#pragma unroll
        for (int ni = 0; ni < 2; ++ni)
#pragma unroll
            for (int r = 0; r < 4; ++r) {
                int row = mi * 16 + (lane >> 4) * 4 + r;
                int col = ni * 16 + (lane & 15);
                zbuf[w][row][col] = acc[mi][ni][r];
            }
    __syncthreads();

    // ---- gates + state update ----
    for (int e = tid; e < BM * BN; e += 256) {
        int r = e >> 5;
        int j = e & 31;
        int row_g = m0 + r;
        int col_g = c0 + j;
        float zi = zbuf[0][r][j] + bias[col_g];
        float zf = zbuf[1][r][j] + bias[512 + col_g];
        float zg = zbuf[2][r][j] + bias[1024 + col_g];
        float zo = zbuf[3][r][j] + bias[1536 + col_g];
        float ig = 1.f / (1.f + expf(-zi));
        float fg = 1.f / (1.f + expf(-zf));
        float gg = tanhf(zg);
        float og = 1.f / (1.f + expf(-zo));
        size_t idx = (size_t)row_g * Hh + col_g;
        float cn = fg * c_st[idx] + ig * gg;
        float hn = og * tanhf(cn);
        c_st[idx] = cn;
        unsigned short hh = f2bf(hn);
        h_hi[idx] = hh;
        h_lo[idx] = f2bf(hn - bf2f(hh));
        int len = lengths[row_g];
        int oidx = len - 1; if (oidx < 0) oidx = 0;
        if (t == oidx) out[idx] = hn;
    }
}

extern "C" void kernel_launch(void* const* d_in, const int* in_sizes, int n_in,
                              void* d_out, int out_size, void* d_ws, size_t ws_size,
                              hipStream_t stream) {
    const float* X = (const float*)d_in[0];
    const int* lengths = (const int*)d_in[1];
    const float* Wx = (const float*)d_in[2];
    const float* Wh = (const float*)d_in[3];
    const float* bias = (const float*)d_in[4];
    float* out = (float*)d_out;

    char* ws = (char*)d_ws;
    unsigned short* WT_hi = (unsigned short*)ws;                          // 4 MB
    unsigned short* WT_lo = (unsigned short*)(ws + (4u << 20));           // 4 MB
    float* c_st = (float*)(ws + (8u << 20));                              // 512 KB
    unsigned short* h_hi = (unsigned short*)(ws + (8u << 20) + (512u << 10)); // 256 KB
    unsigned short* h_lo = (unsigned short*)(ws + (8u << 20) + (768u << 10)); // 256 KB

    hipLaunchKernelGGL(prep_w, dim3(2048), dim3(256), 0, stream, Wx, Wh, WT_hi, WT_lo);
    hipLaunchKernelGGL(init_state, dim3(512), dim3(256), 0, stream, c_st, h_hi, h_lo);
    for (int t = 0; t < Tt; ++t) {
        hipLaunchKernelGGL(lstm_step, dim3(128), dim3(256), 0, stream,
                           X, lengths, WT_hi, WT_lo, bias, c_st, h_hi, h_lo, out, t);
    }
}

// Round 2
// 14083.984 us; speedup vs baseline: 1.1037x; 1.1037x over previous
//
#include <hip/hip_runtime.h>

#define Bb 256
#define Tt 512
#define Dd 512
#define Hh 512
#define KTOT 1024
#define FOURH 2048

typedef __attribute__((ext_vector_type(8))) short bf16x8;
typedef __attribute__((ext_vector_type(4))) float f32x4;

__device__ __forceinline__ unsigned short f2bf(float f) {
    union { float f; unsigned u; } x; x.f = f;
    unsigned u = x.u;
    unsigned r = u + 0x7FFFu + ((u >> 16) & 1u);
    return (unsigned short)(r >> 16);
}
__device__ __forceinline__ float bf2f(unsigned short s) {
    union { unsigned u; float f; } x; x.u = ((unsigned)s) << 16;
    return x.f;
}

// Transpose + split W = [Wx; Wh] (K=1024 rows, N=2048 cols) into
// WT_hi/WT_lo layout [N=2048][K=1024] bf16 (k-contiguous per output column).
__global__ void prep_w(const float* __restrict__ Wx, const float* __restrict__ Wh,
                       unsigned short* __restrict__ WT_hi, unsigned short* __restrict__ WT_lo) {
    __shared__ float tile[32][33];
    int n0 = (blockIdx.x & 63) * 32;
    int k0 = (blockIdx.x >> 6) * 32;
    int tx = threadIdx.x & 31;
    int ty = threadIdx.x >> 5;
    for (int q = 0; q < 4; ++q) {
        int k = k0 + ty + q * 8;
        int n = n0 + tx;
        float v = (k < Dd) ? Wx[(size_t)k * FOURH + n] : Wh[(size_t)(k - Dd) * FOURH + n];
        tile[ty + q * 8][tx] = v;
    }
    __syncthreads();
    for (int q = 0; q < 4; ++q) {
        int nl = ty + q * 8;
        int kl = tx;
        float v = tile[kl][nl];
        unsigned short hi = f2bf(v);
        unsigned short lo = f2bf(v - bf2f(hi));
        size_t o = (size_t)(n0 + nl) * KTOT + (size_t)(k0 + kl);
        WT_hi[o] = hi;
        WT_lo[o] = lo;
    }
}

__global__ void init_state(float* __restrict__ c_st,
                           unsigned short* __restrict__ h_hi,
                           unsigned short* __restrict__ h_lo) {
    int i = blockIdx.x * blockDim.x + threadIdx.x;
    if (i < Bb * Hh) { c_st[i] = 0.f; h_hi[i] = 0; h_lo[i] = 0; }
}

// Split all of X (fp32 [B][T][D]) into bf16 hi/lo arrays, same element order.
__global__ void xsplit(const float* __restrict__ X,
                       ushort4* __restrict__ Xhi, ushort4* __restrict__ Xlo) {
    const long total = (long)Bb * Tt * Dd / 4;   // float4 count
    long stride = (long)gridDim.x * blockDim.x;
    for (long i = (long)blockIdx.x * blockDim.x + threadIdx.x; i < total; i += stride) {
        const float4 v = ((const float4*)X)[i];
        float vv[4] = {v.x, v.y, v.z, v.w};
        ushort4 h4, l4;
        unsigned short* hp = (unsigned short*)&h4;
        unsigned short* lp = (unsigned short*)&l4;
#pragma unroll
        for (int e = 0; e < 4; ++e) {
            unsigned short hi = f2bf(vv[e]);
            hp[e] = hi;
            lp[e] = f2bf(vv[e] - bf2f(hi));
        }
        Xhi[i] = h4;
        Xlo[i] = l4;
    }
}

// One timestep. Grid: 256 WGs x 256 threads.
//   xcd = bx&7, i = bx>>3, row_tile = i&7 (m0 = 32*row_tile),
//   col_sub = i>>3, col_group = xcd*4+col_sub, hc0 = 16*col_group.
// Each XCD owns 4 col_groups => its 256 W-columns (1 MB hi+lo) stay L2-resident.
// Wave w = gate w; per-wave tile 32 rows x 16 cols, K=1024, bf16 split-3 MFMA.
// PRESPLIT: A frags read directly from pre-split Xhi/Xlo + h_hi/h_lo (no LDS, no barriers
// in the K loop). Fallback (!PRESPLIT): x-half staged through LDS with inline conversion.
template<bool PRESPLIT>
__global__ __launch_bounds__(256) void lstm_step2(
    const float* __restrict__ X,
    const unsigned short* __restrict__ Xhi, const unsigned short* __restrict__ Xlo,
    const int* __restrict__ lengths,
    const unsigned short* __restrict__ WT_hi, const unsigned short* __restrict__ WT_lo,
    const float* __restrict__ bias,
    float* __restrict__ c_st, unsigned short* __restrict__ h_hi, unsigned short* __restrict__ h_lo,
    float* __restrict__ out, int t)
{
    __shared__ __align__(16) unsigned short Ahi[32][256 + 8];
    __shared__ __align__(16) unsigned short Alo[32][256 + 8];
    __shared__ float zbuf[4][32][17];

    const int bx = blockIdx.x;
    const int xcd = bx & 7;
    const int i = bx >> 3;
    const int m0 = (i & 7) * 32;
    const int col_group = xcd * 4 + (i >> 3);
    const int hc0 = col_group * 16;
    const int tid = threadIdx.x;
    const int w = tid >> 6;          // gate
    const int lane = tid & 63;

    f32x4 acc[2];
    acc[0] = (f32x4){0.f, 0.f, 0.f, 0.f};
    acc[1] = (f32x4){0.f, 0.f, 0.f, 0.f};

    const int colk = (w * 512 + hc0 + (lane & 15));
    const size_t bbase = (size_t)colk * KTOT;
    const int klo = (lane >> 4) * 8;   // 0,8,16,24

    if constexpr (PRESPLIT) {
#pragma unroll
        for (int ks = 0; ks < 32; ++ks) {
            const int kk = ks * 32 + klo;
            bf16x8 ah[2], al[2], bh, bl;
#pragma unroll
            for (int mi = 0; mi < 2; ++mi) {
                const int row = m0 + mi * 16 + (lane & 15);
                if (kk < Dd) {
                    const size_t ao = ((size_t)row * Tt + t) * Dd + kk;
                    ah[mi] = *(const bf16x8*)&Xhi[ao];
                    al[mi] = *(const bf16x8*)&Xlo[ao];
                } else {
                    const size_t ao = (size_t)row * Hh + (kk - Dd);
                    ah[mi] = *(const bf16x8*)&h_hi[ao];
                    al[mi] = *(const bf16x8*)&h_lo[ao];
                }
            }
            bh = *(const bf16x8*)&WT_hi[bbase + kk];
            bl = *(const bf16x8*)&WT_lo[bbase + kk];
#pragma unroll
            for (int mi = 0; mi < 2; ++mi) {
                acc[mi] = __builtin_amdgcn_mfma_f32_16x16x32_bf16(ah[mi], bh, acc[mi], 0, 0, 0);
                acc[mi] = __builtin_amdgcn_mfma_f32_16x16x32_bf16(ah[mi], bl, acc[mi], 0, 0, 0);
                acc[mi] = __builtin_amdgcn_mfma_f32_16x16x32_bf16(al[mi], bh, acc[mi], 0, 0, 0);
            }
        }
    } else {
        // x-half through LDS with conversion, 2 chunks of 256 k
        for (int ch = 0; ch < 2; ++ch) {
#pragma unroll
            for (int q = 0; q < 8; ++q) {
                int li = tid + q * 256;          // 2048 float4 slots
                int r = li >> 6;                 // 64 float4 per row
                int f4 = li & 63;
                const float4 v = *(const float4*)&X[((size_t)(m0 + r) * Tt + t) * Dd + ch * 256 + f4 * 4];
                float vv[4] = {v.x, v.y, v.z, v.w};
#pragma unroll
                for (int e = 0; e < 4; ++e) {
                    unsigned short hi = f2bf(vv[e]);
                    Ahi[r][f4 * 4 + e] = hi;
                    Alo[r][f4 * 4 + e] = f2bf(vv[e] - bf2f(hi));
                }
            }
            __syncthreads();
#pragma unroll
            for (int ks = 0; ks < 8; ++ks) {
                const int kk = ch * 256 + ks * 32 + klo;
                bf16x8 ah[2], al[2], bh, bl;
#pragma unroll
                for (int mi = 0; mi < 2; ++mi) {
                    const int rl = mi * 16 + (lane & 15);
                    ah[mi] = *(const bf16x8*)&Ahi[rl][ks * 32 + klo];
                    al[mi] = *(const bf16x8*)&Alo[rl][ks * 32 + klo];
                }
                bh = *(const bf16x8*)&WT_hi[bbase + kk];
                bl = *(const bf16x8*)&WT_lo[bbase + kk];
#pragma unroll
                for (int mi = 0; mi < 2; ++mi) {
                    acc[mi] = __builtin_amdgcn_mfma_f32_16x16x32_bf16(ah[mi], bh, acc[mi], 0, 0, 0);
                    acc[mi] = __builtin_amdgcn_mfma_f32_16x16x32_bf16(ah[mi], bl, acc[mi], 0, 0, 0);
                    acc[mi] = __builtin_amdgcn_mfma_f32_16x16x32_bf16(al[mi], bh, acc[mi], 0, 0, 0);
                }
            }
            __syncthreads();
        }
        // h-half direct
#pragma unroll
        for (int ks = 16; ks < 32; ++ks) {
            const int kk = ks * 32 + klo;
            bf16x8 ah[2], al[2], bh, bl;
#pragma unroll
            for (int mi = 0; mi < 2; ++mi) {
                const int row = m0 + mi * 16 + (lane & 15);
                const size_t ao = (size_t)row * Hh + (kk - Dd);
                ah[mi] = *(const bf16x8*)&h_hi[ao];
                al[mi] = *(const bf16x8*)&h_lo[ao];
            }
            bh = *(const bf16x8*)&WT_hi[bbase + kk];
            bl = *(const bf16x8*)&WT_lo[bbase + kk];
#pragma unroll
            for (int mi = 0; mi < 2; ++mi) {
                acc[mi] = __builtin_amdgcn_mfma_f32_16x16x32_bf16(ah[mi], bh, acc[mi], 0, 0, 0);
                acc[mi] = __builtin_amdgcn_mfma_f32_16x16x32_bf16(ah[mi], bl, acc[mi], 0, 0, 0);
                acc[mi] = __builtin_amdgcn_mfma_f32_16x16x32_bf16(al[mi], bh, acc[mi], 0, 0, 0);
            }
        }
    }

    // z tiles -> LDS  (C/D layout: col=lane&15, row=(lane>>4)*4+reg)
#pragma unroll
    for (int mi = 0; mi < 2; ++mi)
#pragma unroll
        for (int r = 0; r < 4; ++r) {
            int row = mi * 16 + (lane >> 4) * 4 + r;
            zbuf[w][row][lane & 15] = acc[mi][r];
        }
    __syncthreads();

    // gates + state update: 32 rows x 16 cols = 512 elems, 2 per thread
    for (int e = tid; e < 32 * 16; e += 256) {
        int r = e >> 4;
        int j = e & 15;
        int row_g = m0 + r;
        int col_g = hc0 + j;
        float zi = zbuf[0][r][j] + bias[col_g];
        float zf = zbuf[1][r][j] + bias[512 + col_g];
        float zg = zbuf[2][r][j] + bias[1024 + col_g];
        float zo = zbuf[3][r][j] + bias[1536 + col_g];
        float ig = 1.f / (1.f + expf(-zi));
        float fg = 1.f / (1.f + expf(-zf));
        float gg = tanhf(zg);
        float og = 1.f / (1.f + expf(-zo));
        size_t idx = (size_t)row_g * Hh + col_g;
        float cn = fg * c_st[idx] + ig * gg;
        float hn = og * tanhf(cn);
        c_st[idx] = cn;
        unsigned short hh = f2bf(hn);
        h_hi[idx] = hh;
        h_lo[idx] = f2bf(hn - bf2f(hh));
        int len = lengths[row_g];
        int oidx = len - 1; if (oidx < 0) oidx = 0;
        if (t == oidx) out[idx] = hn;
    }
}

extern "C" void kernel_launch(void* const* d_in, const int* in_sizes, int n_in,
                              void* d_out, int out_size, void* d_ws, size_t ws_size,
                              hipStream_t stream) {
    const float* X = (const float*)d_in[0];
    const int* lengths = (const int*)d_in[1];
    const float* Wx = (const float*)d_in[2];
    const float* Wh = (const float*)d_in[3];
    const float* bias = (const float*)d_in[4];
    float* out = (float*)d_out;

    char* ws = (char*)d_ws;
    unsigned short* WT_hi = (unsigned short*)ws;                                   // 4 MB
    unsigned short* WT_lo = (unsigned short*)(ws + (4u << 20));                    // 4 MB
    float* c_st = (float*)(ws + (8u << 20));                                       // 512 KB
    unsigned short* h_hi = (unsigned short*)(ws + (8u << 20) + (512u << 10));      // 256 KB
    unsigned short* h_lo = (unsigned short*)(ws + (8u << 20) + (768u << 10));      // 256 KB
    unsigned short* Xhi = (unsigned short*)(ws + (16u << 20));                     // 128 MB
    unsigned short* Xlo = (unsigned short*)(ws + (144u << 20));                    // 128 MB

    const size_t NEED_FULL = (272u << 20);
    const bool presplit = ws_size >= NEED_FULL;

    hipLaunchKernelGGL(prep_w, dim3(2048), dim3(256), 0, stream, Wx, Wh, WT_hi, WT_lo);
    hipLaunchKernelGGL(init_state, dim3(512), dim3(256), 0, stream, c_st, h_hi, h_lo);
    if (presplit) {
        hipLaunchKernelGGL(xsplit, dim3(4096), dim3(256), 0, stream,
                           X, (ushort4*)Xhi, (ushort4*)Xlo);
        for (int t = 0; t < Tt; ++t) {
            hipLaunchKernelGGL(lstm_step2<true>, dim3(256), dim3(256), 0, stream,
                               X, Xhi, Xlo, lengths, WT_hi, WT_lo, bias,
                               c_st, h_hi, h_lo, out, t);
        }
    } else {
        for (int t = 0; t < Tt; ++t) {
            hipLaunchKernelGGL(lstm_step2<false>, dim3(256), dim3(256), 0, stream,
                               X, Xhi, Xlo, lengths, WT_hi, WT_lo, bias,
                               c_st, h_hi, h_lo, out, t);
        }
    }
}